// Round 1
// baseline (526.254 us; speedup 1.0000x reference)
//
#include <hip/hip_runtime.h>
#include <hip/hip_bf16.h>

#define N_TOK 131072
#define NCHUNK 1024
#define NBINS 8192
#define HSTR 8448

typedef __bf16 bf16_t;
typedef bf16_t bf16x4 __attribute__((ext_vector_type(4)));
typedef bf16_t bf16x8 __attribute__((ext_vector_type(8)));
typedef float f32x4 __attribute__((ext_vector_type(4)));
typedef float f32x16 __attribute__((ext_vector_type(16)));

// window key decomposition: key = bwi*4608 + cell  (matches reference _window_keys)
// nwx=nwy=31, nwz=2, mpw=1922, vol=4608; wz==0 always (z<32) but keep general.
__device__ __forceinline__ void win_keys(int b, int z, int y, int x, int r,
                                         int& bwi, int& cell) {
  int wx = x / 12, wy = y / 12, wz = z >> 5;
  int cx = x % 12, cy = y % 12, cz = z & 31;
  if (r == 0) { bwi = b * 1922 + wx * 62 + wy * 2 + wz; cell = cx * 384 + cy * 32 + cz; }
  else        { bwi = b * 1922 + wy * 62 + wx * 2 + wz; cell = cy * 384 + cx * 32 + cz; }
}

// ---- weights prep: f32 -> bf16, transposed to [n][k] for contiguous B-fragments
__global__ void k_prep(const float* __restrict__ Wqkv, const float* __restrict__ Wo,
                       bf16_t* __restrict__ Wt, bf16_t* __restrict__ Wot) {
  int t = blockIdx.x * 256 + threadIdx.x;
  if (t < 98304) {                    // 2 * 384 * 128
    int i = t / 49152, rem = t % 49152, n = rem / 128, k = rem % 128;
    Wt[t] = (bf16_t)Wqkv[(i * 128 + k) * 384 + n];
  } else {
    int u = t - 98304;                // 2 * 128 * 128
    int i = u / 16384, rem = u % 16384, e = rem / 128, d = rem % 128;
    Wot[u] = (bf16_t)Wo[(i * 128 + d) * 128 + e];
  }
}

__global__ void k_hist(const int* __restrict__ coords, int* __restrict__ hist) {
  int t = blockIdx.x * 256 + threadIdx.x;
  int4 c = ((const int4*)coords)[t];    // b,z,y,x
  int bwi, cell;
  win_keys(c.x, c.y, c.z, c.w, 0, bwi, cell);
  atomicAdd(&hist[bwi], 1);
  win_keys(c.x, c.y, c.z, c.w, 1, bwi, cell);
  atomicAdd(&hist[HSTR + bwi], 1);
}

__global__ void k_scan(const int* __restrict__ histb, int* __restrict__ startsb,
                       int* __restrict__ curb) {
  int r = blockIdx.x;
  const int* hist = histb + r * HSTR;
  int* starts = startsb + r * HSTR;
  int* cur = curb + r * HSTR;
  __shared__ int ssum[256];
  int tid = threadIdx.x;
  int base = tid * 32;
  int s = 0;
  for (int j = 0; j < 32; j++) s += hist[base + j];
  ssum[tid] = s;
  __syncthreads();
  if (tid == 0) {
    int acc = 0;
    for (int i = 0; i < 256; i++) { int v = ssum[i]; ssum[i] = acc; acc += v; }
  }
  __syncthreads();
  int run = ssum[tid];
  for (int j = 0; j < 32; j++) {
    starts[base + j] = run; cur[base + j] = run; run += hist[base + j];
  }
  if (tid == 255) starts[NBINS] = run;
}

__global__ void k_scatter(const int* __restrict__ coords, int* __restrict__ cur,
                          int* __restrict__ seg) {
  int t = blockIdx.x * 256 + threadIdx.x;
  int4 c = ((const int4*)coords)[t];
  int bwi, cell;
  win_keys(c.x, c.y, c.z, c.w, 0, bwi, cell);
  seg[atomicAdd(&cur[bwi], 1)] = (cell << 17) | t;
  win_keys(c.x, c.y, c.z, c.w, 1, bwi, cell);
  seg[N_TOK + atomicAdd(&cur[HSTR + bwi], 1)] = (cell << 17) | t;
}

// per-window stable finish: sort segment ascending by packed (cell, idx)
__global__ void k_winsort(const int* __restrict__ startsb, const int* __restrict__ segb,
                          int* __restrict__ orderb) {
  int r = blockIdx.y;
  const int* starts = startsb + r * HSTR;
  const int* seg = segb + r * N_TOK;
  int* order = orderb + r * N_TOK;
  int w = blockIdx.x;
  int s = starts[w], m = starts[w + 1] - s;
  for (int i = threadIdx.x; i < m; i += 256) {
    int v = seg[s + i], rk = 0;
    for (int j = 0; j < m; j++) rk += (seg[s + j] < v);
    order[s + rk] = v & 0x1FFFF;
  }
}

// gather + layernorm -> bf16 in sorted order
__global__ __launch_bounds__(256) void k_ln(const float* __restrict__ x,
    const int* __restrict__ order, const float* __restrict__ g,
    const float* __restrict__ b, bf16_t* __restrict__ h) {
  int chunk = blockIdx.x;
  int l = threadIdx.x & 31;
  float4 gv = ((const float4*)g)[l];
  float4 bv = ((const float4*)b)[l];
  for (int row = threadIdx.x >> 5; row < 128; row += 8) {
    int sp = chunk * 128 + row;
    int tok = order[sp];
    float4 v = ((const float4*)(x + (size_t)tok * 128))[l];
    float s = v.x + v.y + v.z + v.w;
    float sq = v.x * v.x + v.y * v.y + v.z * v.z + v.w * v.w;
    #pragma unroll
    for (int m = 1; m < 32; m <<= 1) { s += __shfl_xor(s, m); sq += __shfl_xor(sq, m); }
    float mean = s * 0.0078125f;
    float var = sq * 0.0078125f - mean * mean;
    float rstd = rsqrtf(var + 1e-5f);
    bf16x4 o;
    o[0] = (bf16_t)((v.x - mean) * rstd * gv.x + bv.x);
    o[1] = (bf16_t)((v.y - mean) * rstd * gv.y + bv.y);
    o[2] = (bf16_t)((v.z - mean) * rstd * gv.z + bv.z);
    o[3] = (bf16_t)((v.w - mean) * rstd * gv.w + bv.w);
    *(bf16x4*)(h + (size_t)sp * 128 + l * 4) = o;
  }
}

// qkv = h @ Wqkv : per block one 128x128 C tile (chunk, nb); 4 waves, 64x64 quadrant each
__global__ __launch_bounds__(256) void k_qkv(const bf16_t* __restrict__ h,
    const bf16_t* __restrict__ Wt, bf16_t* __restrict__ qkv) {
  int chunk = blockIdx.x, nb = blockIdx.y;
  int wv = threadIdx.x >> 6, lane = threadIdx.x & 63;
  int qr = (wv >> 1) * 64, qc = (wv & 1) * 64;
  int l16 = lane & 15, gk = 8 * (lane >> 4);
  const bf16_t* A = h + (size_t)chunk * 128 * 128;
  const bf16_t* B = Wt + (size_t)nb * 128 * 128;
  f32x4 acc[4][4] = {};
  #pragma unroll
  for (int ks = 0; ks < 4; ks++) {
    int k0 = ks * 32 + gk;
    bf16x8 a[4], b[4];
    #pragma unroll
    for (int mi = 0; mi < 4; mi++)
      a[mi] = *(const bf16x8*)(A + (qr + mi * 16 + l16) * 128 + k0);
    #pragma unroll
    for (int ni = 0; ni < 4; ni++)
      b[ni] = *(const bf16x8*)(B + (qc + ni * 16 + l16) * 128 + k0);
    #pragma unroll
    for (int mi = 0; mi < 4; mi++)
      #pragma unroll
      for (int ni = 0; ni < 4; ni++)
        acc[mi][ni] = __builtin_amdgcn_mfma_f32_16x16x32_bf16(a[mi], b[ni], acc[mi][ni], 0, 0, 0);
  }
  int r4 = (lane >> 4) * 4;
  #pragma unroll
  for (int mi = 0; mi < 4; mi++)
    #pragma unroll
    for (int ni = 0; ni < 4; ni++) {
      int col = nb * 128 + qc + ni * 16 + l16;
      #pragma unroll
      for (int e = 0; e < 4; e++) {
        int row = chunk * 128 + qr + mi * 16 + r4 + e;
        qkv[(size_t)row * 384 + col] = (bf16_t)acc[mi][ni][e];
      }
    }
}

// attention per (chunk, head): scores 32x32x16 MFMA + wave softmax + PV 16x16x32
__global__ __launch_bounds__(256) void k_att(const bf16_t* __restrict__ qkv,
                                             bf16_t* __restrict__ ao) {
  int chunk = blockIdx.x >> 3, hh = blockIdx.x & 7;
  __shared__ bf16_t Pb[128 * 128];
  __shared__ bf16_t vT[16 * 136];
  __shared__ float rs[128];
  int tid = threadIdx.x, wv = tid >> 6, lane = tid & 63;
  const bf16_t* base = qkv + (size_t)chunk * 128 * 384;
  { // stage V transposed (vT[d][kk]) so PV B-fragments are contiguous
    int rrow = tid >> 1, hc = (tid & 1) * 8;
    bf16x8 vv = *(const bf16x8*)(base + rrow * 384 + 256 + hh * 16 + hc);
    #pragma unroll
    for (int j = 0; j < 8; j++) vT[(hc + j) * 136 + rrow] = vv[j];
  }
  int l31 = lane & 31, hi = lane >> 5;
  bf16x8 aq = *(const bf16x8*)(base + (32 * wv + l31) * 384 + hh * 16 + 8 * hi);
  f32x16 sc[4] = {};
  #pragma unroll
  for (int t = 0; t < 4; t++) {
    bf16x8 bk = *(const bf16x8*)(base + (32 * t + l31) * 384 + 128 + hh * 16 + 8 * hi);
    sc[t] = __builtin_amdgcn_mfma_f32_32x32x16_bf16(aq, bk, sc[t], 0, 0, 0);
  }
  #pragma unroll
  for (int e = 0; e < 16; e++) {
    float s0 = sc[0][e], s1 = sc[1][e], s2 = sc[2][e], s3 = sc[3][e];
    float mx = fmaxf(fmaxf(s0, s1), fmaxf(s2, s3));
    #pragma unroll
    for (int m = 1; m < 32; m <<= 1) mx = fmaxf(mx, __shfl_xor(mx, m));
    float p0 = __expf(0.25f * (s0 - mx)), p1 = __expf(0.25f * (s1 - mx));
    float p2 = __expf(0.25f * (s2 - mx)), p3 = __expf(0.25f * (s3 - mx));
    float sum = p0 + p1 + p2 + p3;
    #pragma unroll
    for (int m = 1; m < 32; m <<= 1) sum += __shfl_xor(sum, m);
    int row = 32 * wv + (e & 3) + 8 * (e >> 2) + 4 * hi;   // verified 32x32 C layout
    if (l31 == 0) rs[row] = sum;
    int rbase = row * 256, sw = (row & 7) << 4;             // XOR swizzle (G4)
    *(bf16_t*)((char*)Pb + ((rbase + 2 * l31      ) ^ sw)) = (bf16_t)p0;
    *(bf16_t*)((char*)Pb + ((rbase + 2 * l31 +  64) ^ sw)) = (bf16_t)p1;
    *(bf16_t*)((char*)Pb + ((rbase + 2 * l31 + 128) ^ sw)) = (bf16_t)p2;
    *(bf16_t*)((char*)Pb + ((rbase + 2 * l31 + 192) ^ sw)) = (bf16_t)p3;
  }
  __syncthreads();
  int l16 = lane & 15, g4 = lane >> 4;
  f32x4 o0 = {}, o1 = {};
  #pragma unroll
  for (int ks = 0; ks < 4; ks++) {
    bf16x8 vb = *(const bf16x8*)(&vT[l16 * 136 + ks * 32 + 8 * g4]);
    int q0 = 32 * wv + l16, q1 = q0 + 16;
    int kb = (ks * 32 + 8 * g4) * 2;
    bf16x8 pa0 = *(const bf16x8*)((const char*)Pb + ((q0 * 256 + kb) ^ ((q0 & 7) << 4)));
    bf16x8 pa1 = *(const bf16x8*)((const char*)Pb + ((q1 * 256 + kb) ^ ((q1 & 7) << 4)));
    o0 = __builtin_amdgcn_mfma_f32_16x16x32_bf16(pa0, vb, o0, 0, 0, 0);
    o1 = __builtin_amdgcn_mfma_f32_16x16x32_bf16(pa1, vb, o1, 0, 0, 0);
  }
  #pragma unroll
  for (int e = 0; e < 4; e++) {
    int r0 = 32 * wv + g4 * 4 + e;
    int r1 = r0 + 16;
    ao[(size_t)(chunk * 128 + r0) * 128 + hh * 16 + l16] = (bf16_t)(o0[e] / rs[r0]);
    ao[(size_t)(chunk * 128 + r1) * 128 + hh * 16 + l16] = (bf16_t)(o1[e] / rs[r1]);
  }
}

// y = attn_out @ Wo, residual add in f32, scatter back to original token order
__global__ __launch_bounds__(256) void k_out(const bf16_t* __restrict__ ao,
    const bf16_t* __restrict__ Wot, const int* __restrict__ order,
    const float* __restrict__ xin, float* __restrict__ xout) {
  int chunk = blockIdx.x;
  int wv = threadIdx.x >> 6, lane = threadIdx.x & 63;
  int qr = (wv >> 1) * 64, qc = (wv & 1) * 64;
  int l16 = lane & 15, gk = 8 * (lane >> 4);
  const bf16_t* A = ao + (size_t)chunk * 128 * 128;
  f32x4 acc[4][4] = {};
  #pragma unroll
  for (int ks = 0; ks < 4; ks++) {
    int k0 = ks * 32 + gk;
    bf16x8 a[4], b[4];
    #pragma unroll
    for (int mi = 0; mi < 4; mi++)
      a[mi] = *(const bf16x8*)(A + (qr + mi * 16 + l16) * 128 + k0);
    #pragma unroll
    for (int ni = 0; ni < 4; ni++)
      b[ni] = *(const bf16x8*)(Wot + (qc + ni * 16 + l16) * 128 + k0);
    #pragma unroll
    for (int mi = 0; mi < 4; mi++)
      #pragma unroll
      for (int ni = 0; ni < 4; ni++)
        acc[mi][ni] = __builtin_amdgcn_mfma_f32_16x16x32_bf16(a[mi], b[ni], acc[mi][ni], 0, 0, 0);
  }
  int r4 = (lane >> 4) * 4;
  #pragma unroll
  for (int mi = 0; mi < 4; mi++) {
    #pragma unroll
    for (int e = 0; e < 4; e++) {
      int row = qr + mi * 16 + r4 + e;
      int tok = order[chunk * 128 + row];
      #pragma unroll
      for (int ni = 0; ni < 4; ni++) {
        int col = qc + ni * 16 + l16;
        xout[(size_t)tok * 128 + col] = xin[(size_t)tok * 128 + col] + acc[mi][ni][e];
      }
    }
  }
}

extern "C" void kernel_launch(void* const* d_in, const int* in_sizes, int n_in,
                              void* d_out, int out_size, void* d_ws, size_t ws_size,
                              hipStream_t stream) {
  const int* coords = (const int*)d_in[0];
  const float* feats = (const float*)d_in[1];
  const float* Wqkv = (const float*)d_in[2];
  const float* Wo = (const float*)d_in[3];
  const float* ln_g = (const float*)d_in[4];
  const float* ln_b = (const float*)d_in[5];
  float* out = (float*)d_out;

  char* w = (char*)d_ws;
  size_t off = 0;
  auto take = [&](size_t b) { char* p = w + off; off += (b + 255) & ~(size_t)255; return p; };
  int* hist   = (int*)take(2 * HSTR * 4);
  int* starts = (int*)take(2 * HSTR * 4);
  int* cur    = (int*)take(2 * HSTR * 4);
  int* seg    = (int*)take(2 * (size_t)N_TOK * 4);
  int* order  = (int*)take(2 * (size_t)N_TOK * 4);
  bf16_t* Wt  = (bf16_t*)take(2 * 384 * 128 * 2);
  bf16_t* Wot = (bf16_t*)take(2 * 128 * 128 * 2);
  bf16_t* hb  = (bf16_t*)take((size_t)N_TOK * 128 * 2);   // aliased: h (LN out) then attn_out
  bf16_t* qkv = (bf16_t*)take((size_t)N_TOK * 384 * 2);

  k_prep<<<512, 256, 0, stream>>>(Wqkv, Wo, Wt, Wot);
  hipMemsetAsync(hist, 0, 2 * HSTR * 4, stream);
  k_hist<<<512, 256, 0, stream>>>(coords, hist);
  k_scan<<<2, 256, 0, stream>>>(hist, starts, cur);
  k_scatter<<<512, 256, 0, stream>>>(coords, cur, seg);
  k_winsort<<<dim3(NBINS, 2), 256, 0, stream>>>(starts, seg, order);

  for (int r = 0; r < 2; r++) {
    const float* xin = (r == 0) ? feats : out;
    const int* ord = order + r * N_TOK;
    k_ln<<<NCHUNK, 256, 0, stream>>>(xin, ord, ln_g + r * 128, ln_b + r * 128, hb);
    k_qkv<<<dim3(NCHUNK, 3), 256, 0, stream>>>(hb, Wt + r * 49152, qkv);
    k_att<<<NCHUNK * 8, 256, 0, stream>>>(qkv, hb);
    k_out<<<NCHUNK, 256, 0, stream>>>(hb, Wot + r * 16384, ord, xin, out);
  }
}

// Round 2
// 339.542 us; speedup vs baseline: 1.5499x; 1.5499x over previous
//
#include <hip/hip_runtime.h>
#include <hip/hip_bf16.h>

#define N_TOK 131072
#define NCHUNK 1024
#define NBINS 8192
#define HSTR 8448

typedef __bf16 bf16_t;
typedef bf16_t bf16x4 __attribute__((ext_vector_type(4)));
typedef bf16_t bf16x8 __attribute__((ext_vector_type(8)));
typedef float f32x4 __attribute__((ext_vector_type(4)));
typedef float f32x16 __attribute__((ext_vector_type(16)));

__device__ __forceinline__ unsigned pkbf(float a, float b) {
  unsigned r;
  asm("v_cvt_pk_bf16_f32 %0, %1, %2" : "=v"(r) : "v"(a), "v"(b));
  return r;
}
__device__ __forceinline__ void pl32swap(unsigned& x, unsigned& y) {
  asm("v_permlane32_swap_b32 %0, %1" : "+v"(x), "+v"(y));
}

// window key decomposition: key = bwi*4608 + cell  (matches reference _window_keys)
__device__ __forceinline__ void win_keys(int b, int z, int y, int x, int r,
                                         int& bwi, int& cell) {
  int wx = x / 12, wy = y / 12, wz = z >> 5;
  int cx = x % 12, cy = y % 12, cz = z & 31;
  if (r == 0) { bwi = b * 1922 + wx * 62 + wy * 2 + wz; cell = cx * 384 + cy * 32 + cz; }
  else        { bwi = b * 1922 + wy * 62 + wx * 2 + wz; cell = cy * 384 + cx * 32 + cz; }
}

__global__ void k_prep(const float* __restrict__ Wqkv, const float* __restrict__ Wo,
                       bf16_t* __restrict__ Wt, bf16_t* __restrict__ Wot) {
  int t = blockIdx.x * 256 + threadIdx.x;
  if (t < 98304) {                    // 2 * 384 * 128
    int i = t / 49152, rem = t % 49152, n = rem / 128, k = rem % 128;
    Wt[t] = (bf16_t)Wqkv[(i * 128 + k) * 384 + n];
  } else {
    int u = t - 98304;                // 2 * 128 * 128
    int i = u / 16384, rem = u % 16384, e = rem / 128, d = rem % 128;
    Wot[u] = (bf16_t)Wo[(i * 128 + d) * 128 + e];
  }
}

__global__ void k_hist(const int* __restrict__ coords, int* __restrict__ hist) {
  int t = blockIdx.x * 256 + threadIdx.x;
  int4 c = ((const int4*)coords)[t];    // b,z,y,x
  int bwi, cell;
  win_keys(c.x, c.y, c.z, c.w, 0, bwi, cell);
  atomicAdd(&hist[bwi], 1);
  win_keys(c.x, c.y, c.z, c.w, 1, bwi, cell);
  atomicAdd(&hist[HSTR + bwi], 1);
}

__global__ void k_scan(const int* __restrict__ histb, int* __restrict__ startsb,
                       int* __restrict__ curb) {
  int r = blockIdx.x;
  const int* hist = histb + r * HSTR;
  int* starts = startsb + r * HSTR;
  int* cur = curb + r * HSTR;
  __shared__ int ssum[256];
  int tid = threadIdx.x;
  int base = tid * 32;
  int s = 0;
  for (int j = 0; j < 32; j++) s += hist[base + j];
  ssum[tid] = s;
  __syncthreads();
  if (tid == 0) {
    int acc = 0;
    for (int i = 0; i < 256; i++) { int v = ssum[i]; ssum[i] = acc; acc += v; }
  }
  __syncthreads();
  int run = ssum[tid];
  for (int j = 0; j < 32; j++) {
    starts[base + j] = run; cur[base + j] = run; run += hist[base + j];
  }
  if (tid == 255) starts[NBINS] = run;
}

__global__ void k_scatter(const int* __restrict__ coords, int* __restrict__ cur,
                          int* __restrict__ seg) {
  int t = blockIdx.x * 256 + threadIdx.x;
  int4 c = ((const int4*)coords)[t];
  int bwi, cell;
  win_keys(c.x, c.y, c.z, c.w, 0, bwi, cell);
  seg[atomicAdd(&cur[bwi], 1)] = (cell << 17) | t;
  win_keys(c.x, c.y, c.z, c.w, 1, bwi, cell);
  seg[N_TOK + atomicAdd(&cur[HSTR + bwi], 1)] = (cell << 17) | t;
}

// per-window stable finish: sort segment ascending by packed (cell, idx)
__global__ void k_winsort(const int* __restrict__ startsb, const int* __restrict__ segb,
                          int* __restrict__ orderb) {
  int r = blockIdx.y;
  const int* starts = startsb + r * HSTR;
  const int* seg = segb + r * N_TOK;
  int* order = orderb + r * N_TOK;
  int w = blockIdx.x;
  int s = starts[w], m = starts[w + 1] - s;
  for (int i = threadIdx.x; i < m; i += 256) {
    int v = seg[s + i], rk = 0;
    for (int j = 0; j < m; j++) rk += (seg[s + j] < v);
    order[s + rk] = v & 0x1FFFF;
  }
}

// gather + layernorm -> bf16 in sorted order
__global__ __launch_bounds__(256) void k_ln(const float* __restrict__ x,
    const int* __restrict__ order, const float* __restrict__ g,
    const float* __restrict__ b, bf16_t* __restrict__ h) {
  int chunk = blockIdx.x;
  int l = threadIdx.x & 31;
  float4 gv = ((const float4*)g)[l];
  float4 bv = ((const float4*)b)[l];
  for (int row = threadIdx.x >> 5; row < 128; row += 8) {
    int sp = chunk * 128 + row;
    int tok = order[sp];
    float4 v = ((const float4*)(x + (size_t)tok * 128))[l];
    float s = v.x + v.y + v.z + v.w;
    float sq = v.x * v.x + v.y * v.y + v.z * v.z + v.w * v.w;
    #pragma unroll
    for (int m = 1; m < 32; m <<= 1) { s += __shfl_xor(s, m); sq += __shfl_xor(sq, m); }
    float mean = s * 0.0078125f;
    float var = sq * 0.0078125f - mean * mean;
    float rstd = rsqrtf(var + 1e-5f);
    bf16x4 o;
    o[0] = (bf16_t)((v.x - mean) * rstd * gv.x + bv.x);
    o[1] = (bf16_t)((v.y - mean) * rstd * gv.y + bv.y);
    o[2] = (bf16_t)((v.z - mean) * rstd * gv.z + bv.z);
    o[3] = (bf16_t)((v.w - mean) * rstd * gv.w + bv.w);
    *(bf16x4*)(h + (size_t)sp * 128 + l * 4) = o;
  }
}

// qkv = h @ Wqkv : per block one 128x128 C tile (chunk, nb); 4 waves, 64x64 quadrant each
__global__ __launch_bounds__(256) void k_qkv(const bf16_t* __restrict__ h,
    const bf16_t* __restrict__ Wt, bf16_t* __restrict__ qkv) {
  int chunk = blockIdx.x, nb = blockIdx.y;
  int wv = threadIdx.x >> 6, lane = threadIdx.x & 63;
  int qr = (wv >> 1) * 64, qc = (wv & 1) * 64;
  int l16 = lane & 15, gk = 8 * (lane >> 4);
  const bf16_t* A = h + (size_t)chunk * 128 * 128;
  const bf16_t* B = Wt + (size_t)nb * 128 * 128;
  f32x4 acc[4][4] = {};
  #pragma unroll
  for (int ks = 0; ks < 4; ks++) {
    int k0 = ks * 32 + gk;
    bf16x8 a[4], b[4];
    #pragma unroll
    for (int mi = 0; mi < 4; mi++)
      a[mi] = *(const bf16x8*)(A + (qr + mi * 16 + l16) * 128 + k0);
    #pragma unroll
    for (int ni = 0; ni < 4; ni++)
      b[ni] = *(const bf16x8*)(B + (qc + ni * 16 + l16) * 128 + k0);
    #pragma unroll
    for (int mi = 0; mi < 4; mi++)
      #pragma unroll
      for (int ni = 0; ni < 4; ni++)
        acc[mi][ni] = __builtin_amdgcn_mfma_f32_16x16x32_bf16(a[mi], b[ni], acc[mi][ni], 0, 0, 0);
  }
  int r4 = (lane >> 4) * 4;
  #pragma unroll
  for (int mi = 0; mi < 4; mi++)
    #pragma unroll
    for (int ni = 0; ni < 4; ni++) {
      int col = nb * 128 + qc + ni * 16 + l16;
      #pragma unroll
      for (int e = 0; e < 4; e++) {
        int row = chunk * 128 + qr + mi * 16 + r4 + e;
        qkv[(size_t)row * 384 + col] = (bf16_t)acc[mi][ni][e];
      }
    }
}

// Fused attention (all 8 heads, swapped QK^T, in-register softmax, reg-built PV)
// + output projection + residual scatter. One block per chunk, 8 waves = 8 heads.
#define VSW(d) ((((d) >> 3) & 7) << 4)
__global__ __launch_bounds__(512, 4) void k_att_out(const bf16_t* __restrict__ qkv,
    const bf16_t* __restrict__ Wot, const int* __restrict__ order,
    const float* __restrict__ xin, float* __restrict__ xout) {
  int chunk = blockIdx.x;
  __shared__ bf16_t vT[8 * 16 * 136];   // V^T per head: vT[d][k], swizzled, 34816 B
  __shared__ bf16_t aoL[128 * 136];     // attention out [q][d], 34816 B
  int tid = threadIdx.x, wv = tid >> 6, lane = tid & 63;
  int l31 = lane & 31, hi = lane >> 5;
  const bf16_t* base = qkv + (size_t)chunk * 128 * 384;

  // stage V transposed+swizzled (coalesced global reads, 2-way-max LDS writes)
  #pragma unroll
  for (int i = 0; i < 4; i++) {
    int t = tid + 512 * i;
    int rr = t >> 4, seg = t & 15;
    bf16x8 vv = *(const bf16x8*)(base + rr * 384 + 256 + seg * 8);
    #pragma unroll
    for (int j = 0; j < 8; j++) {
      int d = seg * 8 + j;
      *(bf16_t*)((char*)vT + ((d * 272 + rr * 2) ^ VSW(d))) = vv[j];
    }
  }
  // K fragments for head wv (A-operand of swapped QK^T: row=k_token, kk=hd)
  bf16x8 kf[4];
  #pragma unroll
  for (int kt = 0; kt < 4; kt++)
    kf[kt] = *(const bf16x8*)(base + (32 * kt + l31) * 384 + 128 + wv * 16 + 8 * hi);
  __syncthreads();

  #pragma unroll 1
  for (int qt = 0; qt < 4; qt++) {
    // Q fragment (B-operand: col=q, kk=hd)
    bf16x8 qf = *(const bf16x8*)(base + (32 * qt + l31) * 384 + wv * 16 + 8 * hi);
    f32x16 sc[4];
    #pragma unroll
    for (int kt = 0; kt < 4; kt++) {
      f32x16 z = {};
      sc[kt] = __builtin_amdgcn_mfma_f32_32x32x16_bf16(kf[kt], qf, z, 0, 0, 0);
    }
    // in-register softmax: lane owns q=l31, its 64 of 128 k; one cross-hi shfl
    float mx = -1e30f;
    #pragma unroll
    for (int t = 0; t < 4; t++)
      #pragma unroll
      for (int e = 0; e < 16; e++) mx = fmaxf(mx, sc[t][e]);
    mx = fmaxf(mx, __shfl_xor(mx, 32));
    float sum = 0.f;
    #pragma unroll
    for (int t = 0; t < 4; t++)
      #pragma unroll
      for (int e = 0; e < 16; e++) {
        float p = __expf(0.25f * (sc[t][e] - mx));
        sc[t][e] = p; sum += p;
      }
    sum += __shfl_xor(sum, 32);
    float inv = 1.0f / sum;
    // PV: build P A-fragments in-register (cvt_pk + permlane32_swap), V from LDS
    f32x16 C = {};
    #pragma unroll
    for (int s = 0; s < 8; s++) {
      int t = s >> 1, sl = (s & 1) * 8;
      unsigned X0 = pkbf(sc[t][sl + 0], sc[t][sl + 1]);
      unsigned X1 = pkbf(sc[t][sl + 2], sc[t][sl + 3]);
      unsigned Y0 = pkbf(sc[t][sl + 4], sc[t][sl + 5]);
      unsigned Y1 = pkbf(sc[t][sl + 6], sc[t][sl + 7]);
      pl32swap(X0, Y0);   // -> frag words w0 (all lanes), w2 (all lanes)
      pl32swap(X1, Y1);   // -> w1, w3
      uint4 fw = {X0, X1, Y0, Y1};
      bf16x8 pf = __builtin_bit_cast(bf16x8, fw);
      int d = wv * 16 + (l31 & 15);
      bf16x8 vf = *(const bf16x8*)((const char*)vT +
                   ((d * 272 + (16 * s + 8 * hi) * 2) ^ VSW(d)));
      C = __builtin_amdgcn_mfma_f32_32x32x16_bf16(pf, vf, C, 0, 0, 0);
    }
    // epilogue: C[row=crow(e,hi)][col=d=l31(<16)]; normalize and park in LDS
    #pragma unroll
    for (int e = 0; e < 16; e++) {
      int row = (e & 3) + 8 * (e >> 2) + 4 * hi;
      float rsv = __shfl(inv, row, 32);
      if (l31 < 16)
        aoL[(32 * qt + row) * 136 + wv * 16 + l31] = (bf16_t)(C[e] * rsv);
    }
  }
  __syncthreads();

  // out-projection GEMM (128x128x128) + f32 residual, scatter to token order
  int wr = wv >> 2, wc = wv & 3;
  int qr = wr * 64, qc = wc * 32;
  int l16 = lane & 15, g4 = lane >> 4;
  f32x4 acc[4][2] = {};
  #pragma unroll
  for (int ks = 0; ks < 4; ks++) {
    int k0 = ks * 32 + 8 * g4;
    bf16x8 a[4], b[2];
    #pragma unroll
    for (int mi = 0; mi < 4; mi++)
      a[mi] = *(const bf16x8*)(&aoL[(qr + mi * 16 + l16) * 136 + k0]);
    #pragma unroll
    for (int ni = 0; ni < 2; ni++)
      b[ni] = *(const bf16x8*)(Wot + (qc + ni * 16 + l16) * 128 + k0);
    #pragma unroll
    for (int mi = 0; mi < 4; mi++)
      #pragma unroll
      for (int ni = 0; ni < 2; ni++)
        acc[mi][ni] = __builtin_amdgcn_mfma_f32_16x16x32_bf16(a[mi], b[ni], acc[mi][ni], 0, 0, 0);
  }
  int r4 = g4 * 4;
  #pragma unroll
  for (int mi = 0; mi < 4; mi++) {
    #pragma unroll
    for (int e = 0; e < 4; e++) {
      int row = qr + mi * 16 + r4 + e;
      int tok = order[chunk * 128 + row];
      #pragma unroll
      for (int ni = 0; ni < 2; ni++) {
        int col = qc + ni * 16 + l16;
        xout[(size_t)tok * 128 + col] = xin[(size_t)tok * 128 + col] + acc[mi][ni][e];
      }
    }
  }
}

extern "C" void kernel_launch(void* const* d_in, const int* in_sizes, int n_in,
                              void* d_out, int out_size, void* d_ws, size_t ws_size,
                              hipStream_t stream) {
  const int* coords = (const int*)d_in[0];
  const float* feats = (const float*)d_in[1];
  const float* Wqkv = (const float*)d_in[2];
  const float* Wo = (const float*)d_in[3];
  const float* ln_g = (const float*)d_in[4];
  const float* ln_b = (const float*)d_in[5];
  float* out = (float*)d_out;

  char* w = (char*)d_ws;
  size_t off = 0;
  auto take = [&](size_t b) { char* p = w + off; off += (b + 255) & ~(size_t)255; return p; };
  int* hist   = (int*)take(2 * HSTR * 4);
  int* starts = (int*)take(2 * HSTR * 4);
  int* cur    = (int*)take(2 * HSTR * 4);
  int* seg    = (int*)take(2 * (size_t)N_TOK * 4);
  int* order  = (int*)take(2 * (size_t)N_TOK * 4);
  bf16_t* Wt  = (bf16_t*)take(2 * 384 * 128 * 2);
  bf16_t* Wot = (bf16_t*)take(2 * 128 * 128 * 2);
  bf16_t* hb  = (bf16_t*)take((size_t)N_TOK * 128 * 2);
  bf16_t* qkv = (bf16_t*)take((size_t)N_TOK * 384 * 2);

  k_prep<<<512, 256, 0, stream>>>(Wqkv, Wo, Wt, Wot);
  hipMemsetAsync(hist, 0, 2 * HSTR * 4, stream);
  k_hist<<<512, 256, 0, stream>>>(coords, hist);
  k_scan<<<2, 256, 0, stream>>>(hist, starts, cur);
  k_scatter<<<512, 256, 0, stream>>>(coords, cur, seg);
  k_winsort<<<dim3(NBINS, 2), 256, 0, stream>>>(starts, seg, order);

  for (int r = 0; r < 2; r++) {
    const float* xin = (r == 0) ? feats : out;
    const int* ord = order + r * N_TOK;
    k_ln<<<NCHUNK, 256, 0, stream>>>(xin, ord, ln_g + r * 128, ln_b + r * 128, hb);
    k_qkv<<<dim3(NCHUNK, 3), 256, 0, stream>>>(hb, Wt + r * 49152, qkv);
    k_att_out<<<NCHUNK, 512, 0, stream>>>(qkv, Wot + r * 16384, ord, xin, out);
  }
}

// Round 3
// 276.563 us; speedup vs baseline: 1.9028x; 1.2277x over previous
//
#include <hip/hip_runtime.h>
#include <hip/hip_bf16.h>

#define N_TOK 131072
#define NCHUNK 1024
#define NBINS 8192
#define HSTR 8448

typedef __bf16 bf16_t;
typedef bf16_t bf16x4 __attribute__((ext_vector_type(4)));
typedef bf16_t bf16x8 __attribute__((ext_vector_type(8)));
typedef float f32x4 __attribute__((ext_vector_type(4)));
typedef float f32x16 __attribute__((ext_vector_type(16)));

__device__ __forceinline__ unsigned pkbf(float a, float b) {
  unsigned r;
  asm("v_cvt_pk_bf16_f32 %0, %1, %2" : "=v"(r) : "v"(a), "v"(b));
  return r;
}
__device__ __forceinline__ void pl32swap(unsigned& x, unsigned& y) {
  asm("v_permlane32_swap_b32 %0, %1" : "+v"(x), "+v"(y));
}

// window key decomposition (matches reference _window_keys)
__device__ __forceinline__ void win_keys(int b, int z, int y, int x, int r,
                                         int& bwi, int& cell) {
  int wx = x / 12, wy = y / 12, wz = z >> 5;
  int cx = x % 12, cy = y % 12, cz = z & 31;
  if (r == 0) { bwi = b * 1922 + wx * 62 + wy * 2 + wz; cell = cx * 384 + cy * 32 + cz; }
  else        { bwi = b * 1922 + wy * 62 + wx * 2 + wz; cell = cy * 384 + cx * 32 + cz; }
}

__global__ void k_prep(const float* __restrict__ Wqkv, const float* __restrict__ Wo,
                       bf16_t* __restrict__ Wt, bf16_t* __restrict__ Wot) {
  int t = blockIdx.x * 256 + threadIdx.x;
  if (t < 98304) {                    // 2 * 384 * 128, [i][n][k]
    int i = t / 49152, rem = t % 49152, n = rem / 128, k = rem % 128;
    Wt[t] = (bf16_t)Wqkv[(i * 128 + k) * 384 + n];
  } else {
    int u = t - 98304;                // 2 * 128 * 128, [i][e][d]
    int i = u / 16384, rem = u % 16384, e = rem / 128, d = rem % 128;
    Wot[u] = (bf16_t)Wo[(i * 128 + d) * 128 + e];
  }
}

__global__ void k_hist(const int* __restrict__ coords, int* __restrict__ hist) {
  int t = blockIdx.x * 256 + threadIdx.x;
  int4 c = ((const int4*)coords)[t];    // b,z,y,x
  int bwi, cell;
  win_keys(c.x, c.y, c.z, c.w, 0, bwi, cell);
  atomicAdd(&hist[bwi], 1);
  win_keys(c.x, c.y, c.z, c.w, 1, bwi, cell);
  atomicAdd(&hist[HSTR + bwi], 1);
}

__global__ void k_scan(const int* __restrict__ histb, int* __restrict__ startsb,
                       int* __restrict__ curb) {
  int r = blockIdx.x;
  const int* hist = histb + r * HSTR;
  int* starts = startsb + r * HSTR;
  int* cur = curb + r * HSTR;
  __shared__ int ssum[256];
  int tid = threadIdx.x;
  int base = tid * 32;
  int s = 0;
  for (int j = 0; j < 32; j++) s += hist[base + j];
  ssum[tid] = s;
  __syncthreads();
  if (tid == 0) {
    int acc = 0;
    for (int i = 0; i < 256; i++) { int v = ssum[i]; ssum[i] = acc; acc += v; }
  }
  __syncthreads();
  int run = ssum[tid];
  for (int j = 0; j < 32; j++) {
    starts[base + j] = run; cur[base + j] = run; run += hist[base + j];
  }
  if (tid == 255) starts[NBINS] = run;
}

__global__ void k_scatter(const int* __restrict__ coords, int* __restrict__ cur,
                          int* __restrict__ seg) {
  int t = blockIdx.x * 256 + threadIdx.x;
  int4 c = ((const int4*)coords)[t];
  int bwi, cell;
  win_keys(c.x, c.y, c.z, c.w, 0, bwi, cell);
  seg[atomicAdd(&cur[bwi], 1)] = (cell << 17) | t;
  win_keys(c.x, c.y, c.z, c.w, 1, bwi, cell);
  seg[N_TOK + atomicAdd(&cur[HSTR + bwi], 1)] = (cell << 17) | t;
}

// per-window stable finish: sort segment ascending by packed (cell, idx)
__global__ void k_winsort(const int* __restrict__ startsb, const int* __restrict__ segb,
                          int* __restrict__ orderb) {
  int r = blockIdx.y;
  const int* starts = startsb + r * HSTR;
  const int* seg = segb + r * N_TOK;
  int* order = orderb + r * N_TOK;
  int w = blockIdx.x;
  int s = starts[w], m = starts[w + 1] - s;
  for (int i = threadIdx.x; i < m; i += 256) {
    int v = seg[s + i], rk = 0;
    for (int j = 0; j < m; j++) rk += (seg[s + j] < v);
    order[s + rk] = v & 0x1FFFF;
  }
}

// ======================== fully fused per-chunk block ========================
// LDS: hL[128][136] (LN out, later aliased as attention-out)  34816 B
//      qkL[128][264] ([tok][n]: Q=0..127, K=128..255, pad 8)  67584 B
//      vT [128][136] (V^T [d][tok], XOR-swizzled)             34816 B
#define VSW(d) ((((d) >> 3) & 7) << 4)
__global__ __launch_bounds__(512, 2) void k_fused(
    const bf16_t* __restrict__ Wt, const bf16_t* __restrict__ Wot,
    const int* __restrict__ order, const float* __restrict__ ln_g,
    const float* __restrict__ ln_b, const float* __restrict__ xin,
    float* __restrict__ xout) {
  int chunk = blockIdx.x;
  __shared__ bf16_t hL[128 * 136];
  __shared__ bf16_t qkL[128 * 264];
  __shared__ bf16_t vT[128 * 136];
  int tid = threadIdx.x, wv = tid >> 6, lane = tid & 63;
  int l16 = lane & 15, gk = 8 * (lane >> 4), r4 = (lane >> 4) * 4;
  int l31 = lane & 31, hi = lane >> 5;

  // ---- phase 0: gather + layernorm -> hL (4 threads per row)
  {
    int row = tid >> 2, g = tid & 3;
    int tok = order[chunk * 128 + row];
    const float4* src = (const float4*)(xin + (size_t)tok * 128) + g * 8;
    float4 v[8];
    #pragma unroll
    for (int j = 0; j < 8; j++) v[j] = src[j];
    float s = 0.f, sq = 0.f;
    #pragma unroll
    for (int j = 0; j < 8; j++) {
      s += v[j].x + v[j].y + v[j].z + v[j].w;
      sq += v[j].x * v[j].x + v[j].y * v[j].y + v[j].z * v[j].z + v[j].w * v[j].w;
    }
    s += __shfl_xor(s, 1); sq += __shfl_xor(sq, 1);
    s += __shfl_xor(s, 2); sq += __shfl_xor(sq, 2);
    float mean = s * 0.0078125f;
    float var = sq * 0.0078125f - mean * mean;
    float rstd = rsqrtf(var + 1e-5f);
    #pragma unroll
    for (int j = 0; j < 8; j++) {
      float4 gv = ((const float4*)ln_g)[g * 8 + j];
      float4 bv = ((const float4*)ln_b)[g * 8 + j];
      bf16x4 o;
      o[0] = (bf16_t)((v[j].x - mean) * rstd * gv.x + bv.x);
      o[1] = (bf16_t)((v[j].y - mean) * rstd * gv.y + bv.y);
      o[2] = (bf16_t)((v[j].z - mean) * rstd * gv.z + bv.z);
      o[3] = (bf16_t)((v[j].w - mean) * rstd * gv.w + bv.w);
      *(bf16x4*)(&hL[row * 136 + g * 32 + j * 4]) = o;
    }
  }
  __syncthreads();

  // ---- phase A: QK projection, swapped operands: C[n=0..255][tok]
  {
    int wr = wv >> 1, wc = wv & 1;       // 64-n block, 64-tok block
    f32x4 acc[4][4] = {};
    #pragma unroll
    for (int ks = 0; ks < 4; ks++) {
      int k0 = ks * 32 + gk;
      bf16x8 a[4], b[4];
      #pragma unroll
      for (int mi = 0; mi < 4; mi++)
        a[mi] = *(const bf16x8*)(Wt + (size_t)(wr * 64 + mi * 16 + l16) * 128 + k0);
      #pragma unroll
      for (int ni = 0; ni < 4; ni++)
        b[ni] = *(const bf16x8*)(&hL[(wc * 64 + ni * 16 + l16) * 136 + k0]);
      #pragma unroll
      for (int mi = 0; mi < 4; mi++)
        #pragma unroll
        for (int ni = 0; ni < 4; ni++)
          acc[mi][ni] = __builtin_amdgcn_mfma_f32_16x16x32_bf16(a[mi], b[ni], acc[mi][ni], 0, 0, 0);
    }
    #pragma unroll
    for (int mi = 0; mi < 4; mi++)
      #pragma unroll
      for (int ni = 0; ni < 4; ni++) {
        int nb = wr * 64 + mi * 16 + r4;
        int tok = wc * 64 + ni * 16 + l16;
        bf16x4 o;
        #pragma unroll
        for (int e = 0; e < 4; e++) o[e] = (bf16_t)acc[mi][ni][e];
        *(bf16x4*)(&qkL[tok * 264 + nb]) = o;
      }
  }

  // ---- phase B: V projection: C[tok][d], scatter to swizzled vT[d][tok]
  {
    int wr = wv >> 2, wc = wv & 3;       // 64-tok block, 32-d block
    f32x4 acc[4][2] = {};
    #pragma unroll
    for (int ks = 0; ks < 4; ks++) {
      int k0 = ks * 32 + gk;
      bf16x8 a[4], b[2];
      #pragma unroll
      for (int mi = 0; mi < 4; mi++)
        a[mi] = *(const bf16x8*)(&hL[(wr * 64 + mi * 16 + l16) * 136 + k0]);
      #pragma unroll
      for (int ni = 0; ni < 2; ni++)
        b[ni] = *(const bf16x8*)(Wt + (size_t)(256 + wc * 32 + ni * 16 + l16) * 128 + k0);
      #pragma unroll
      for (int mi = 0; mi < 4; mi++)
        #pragma unroll
        for (int ni = 0; ni < 2; ni++)
          acc[mi][ni] = __builtin_amdgcn_mfma_f32_16x16x32_bf16(a[mi], b[ni], acc[mi][ni], 0, 0, 0);
    }
    #pragma unroll
    for (int mi = 0; mi < 4; mi++)
      #pragma unroll
      for (int ni = 0; ni < 2; ni++) {
        int d = wc * 32 + ni * 16 + l16;
        int tok0 = wr * 64 + mi * 16 + r4;
        bf16x4 o;
        #pragma unroll
        for (int e = 0; e < 4; e++) o[e] = (bf16_t)acc[mi][ni][e];
        *(bf16x4*)((char*)vT + ((d * 272 + tok0 * 2) ^ VSW(d))) = o;
      }
  }
  __syncthreads();

  // ---- phase C: attention, wave = head; Q/K fragments from LDS
  {
    bf16x8 kf[4];
    #pragma unroll
    for (int kt = 0; kt < 4; kt++)
      kf[kt] = *(const bf16x8*)(&qkL[(32 * kt + l31) * 264 + 128 + wv * 16 + 8 * hi]);
    #pragma unroll 1
    for (int qt = 0; qt < 4; qt++) {
      bf16x8 qf = *(const bf16x8*)(&qkL[(32 * qt + l31) * 264 + wv * 16 + 8 * hi]);
      f32x16 sc[4];
      #pragma unroll
      for (int kt = 0; kt < 4; kt++) {
        f32x16 z = {};
        sc[kt] = __builtin_amdgcn_mfma_f32_32x32x16_bf16(kf[kt], qf, z, 0, 0, 0);
      }
      float mx = -1e30f;
      #pragma unroll
      for (int t = 0; t < 4; t++)
        #pragma unroll
        for (int e = 0; e < 16; e++) mx = fmaxf(mx, sc[t][e]);
      mx = fmaxf(mx, __shfl_xor(mx, 32));
      float sum = 0.f;
      #pragma unroll
      for (int t = 0; t < 4; t++)
        #pragma unroll
        for (int e = 0; e < 16; e++) {
          float p = __expf(0.25f * (sc[t][e] - mx));
          sc[t][e] = p; sum += p;
        }
      sum += __shfl_xor(sum, 32);
      float inv = 1.0f / sum;
      f32x16 C = {};
      #pragma unroll
      for (int s = 0; s < 8; s++) {
        int t = s >> 1, sl = (s & 1) * 8;
        unsigned X0 = pkbf(sc[t][sl + 0] * inv, sc[t][sl + 1] * inv);
        unsigned X1 = pkbf(sc[t][sl + 2] * inv, sc[t][sl + 3] * inv);
        unsigned Y0 = pkbf(sc[t][sl + 4] * inv, sc[t][sl + 5] * inv);
        unsigned Y1 = pkbf(sc[t][sl + 6] * inv, sc[t][sl + 7] * inv);
        pl32swap(X0, Y0);
        pl32swap(X1, Y1);
        uint4 fw = {X0, X1, Y0, Y1};
        bf16x8 pf = __builtin_bit_cast(bf16x8, fw);
        int d = wv * 16 + (l31 & 15);
        bf16x8 vf = *(const bf16x8*)((const char*)vT +
                     ((d * 272 + (16 * s + 8 * hi) * 2) ^ VSW(d)));
        C = __builtin_amdgcn_mfma_f32_32x32x16_bf16(pf, vf, C, 0, 0, 0);
      }
      #pragma unroll
      for (int e = 0; e < 16; e++) {
        int row = (e & 3) + 8 * (e >> 2) + 4 * hi;
        if (l31 < 16)
          hL[(32 * qt + row) * 136 + wv * 16 + l31] = (bf16_t)C[e];   // aoL alias
      }
    }
  }
  __syncthreads();

  // ---- phase D: out-projection + f32 residual, scatter to token order
  {
    int wr = wv >> 2, wc = wv & 3;
    int qr = wr * 64, qc = wc * 32;
    f32x4 acc[4][2] = {};
    #pragma unroll
    for (int ks = 0; ks < 4; ks++) {
      int k0 = ks * 32 + gk;
      bf16x8 a[4], b[2];
      #pragma unroll
      for (int mi = 0; mi < 4; mi++)
        a[mi] = *(const bf16x8*)(&hL[(qr + mi * 16 + l16) * 136 + k0]);
      #pragma unroll
      for (int ni = 0; ni < 2; ni++)
        b[ni] = *(const bf16x8*)(Wot + (qc + ni * 16 + l16) * 128 + k0);
      #pragma unroll
      for (int mi = 0; mi < 4; mi++)
        #pragma unroll
        for (int ni = 0; ni < 2; ni++)
          acc[mi][ni] = __builtin_amdgcn_mfma_f32_16x16x32_bf16(a[mi], b[ni], acc[mi][ni], 0, 0, 0);
    }
    #pragma unroll
    for (int mi = 0; mi < 4; mi++) {
      #pragma unroll
      for (int e = 0; e < 4; e++) {
        int row = qr + mi * 16 + r4 + e;
        int tok = order[chunk * 128 + row];
        #pragma unroll
        for (int ni = 0; ni < 2; ni++) {
          int col = qc + ni * 16 + l16;
          xout[(size_t)tok * 128 + col] = xin[(size_t)tok * 128 + col] + acc[mi][ni][e];
        }
      }
    }
  }
}

extern "C" void kernel_launch(void* const* d_in, const int* in_sizes, int n_in,
                              void* d_out, int out_size, void* d_ws, size_t ws_size,
                              hipStream_t stream) {
  const int* coords = (const int*)d_in[0];
  const float* feats = (const float*)d_in[1];
  const float* Wqkv = (const float*)d_in[2];
  const float* Wo = (const float*)d_in[3];
  const float* ln_g = (const float*)d_in[4];
  const float* ln_b = (const float*)d_in[5];
  float* out = (float*)d_out;

  char* w = (char*)d_ws;
  size_t off = 0;
  auto take = [&](size_t b) { char* p = w + off; off += (b + 255) & ~(size_t)255; return p; };
  int* hist   = (int*)take(2 * HSTR * 4);
  int* starts = (int*)take(2 * HSTR * 4);
  int* cur    = (int*)take(2 * HSTR * 4);
  int* seg    = (int*)take(2 * (size_t)N_TOK * 4);
  int* order  = (int*)take(2 * (size_t)N_TOK * 4);
  bf16_t* Wt  = (bf16_t*)take(2 * 384 * 128 * 2);
  bf16_t* Wot = (bf16_t*)take(2 * 128 * 128 * 2);

  k_prep<<<512, 256, 0, stream>>>(Wqkv, Wo, Wt, Wot);
  hipMemsetAsync(hist, 0, 2 * HSTR * 4, stream);
  k_hist<<<512, 256, 0, stream>>>(coords, hist);
  k_scan<<<2, 256, 0, stream>>>(hist, starts, cur);
  k_scatter<<<512, 256, 0, stream>>>(coords, cur, seg);
  k_winsort<<<dim3(NBINS, 2), 256, 0, stream>>>(starts, seg, order);

  for (int r = 0; r < 2; r++) {
    const float* xin = (r == 0) ? feats : out;
    k_fused<<<NCHUNK, 512, 0, stream>>>(Wt + r * 49152, Wot + r * 16384,
                                        order + r * N_TOK, ln_g + r * 128,
                                        ln_b + r * 128, xin, out);
  }
}